// Round 8
// baseline (2247.213 us; speedup 1.0000x reference)
//
#include <hip/hip_runtime.h>

#define B_ 64
#define T_ 1024
#define I_ 16
#define H_ 512
#define O_ 3
#define NIN_ 103
#define NEX_ 409

// two-level i8 h encoding: h ~= S1*a + S2*b, exact i32 dots, fp32 combine
#define S1q (16.0f / 127.0f)
#define IS1q (127.0f / 16.0f)
#define S2q (S1q / 240.0f)
#define IS2q (240.0f * 127.0f / 16.0f)

#define XI_BYTES ((size_t)B_ * T_ * H_ * 4)  // 134217728

__device__ __forceinline__ int sdot4(unsigned a, unsigned b, int c) {
  return __builtin_amdgcn_sdot4((int)a, (int)b, c, false);
}
__device__ __forceinline__ float f16lo(unsigned u) {
  return (float)__builtin_bit_cast(_Float16, (unsigned short)(u & 0xffffu));
}
__device__ __forceinline__ float f16hi(unsigned u) {
  return (float)__builtin_bit_cast(_Float16, (unsigned short)(u >> 16));
}

// ---------------------------------------------------------------------------
// xi precompute: xi[bt][r] = x[bt] . W_i2h[r] + b_i2h[r] + b_h2h[r]
// Memory-bound on the 134MB write; W rows stay L1/L2-resident.
// ---------------------------------------------------------------------------
__global__ __launch_bounds__(256) void xi_pre_kernel(
    const float* __restrict__ x, const float* __restrict__ W_i2h,
    const float* __restrict__ b_i2h, const float* __restrict__ b_h2h,
    float* __restrict__ xi) {
  const size_t total = (size_t)B_ * T_ * H_;
  size_t idx = (size_t)blockIdx.x * 256 + threadIdx.x;
  const size_t stride = (size_t)gridDim.x * 256;
  for (; idx < total; idx += stride) {
    const size_t bt = idx >> 9;
    const int r = (int)(idx & (H_ - 1));
    const float* xr = x + bt * I_;
    const float* wr = W_i2h + (size_t)r * I_;
    float s = b_i2h[r] + b_h2h[r];
#pragma unroll
    for (int i = 0; i < I_; ++i) s += wr[i] * xr[i];
    xi[idx] = s;
  }
}

// ---------------------------------------------------------------------------
// Single-CU-per-batch RNN. Block b owns batch b fully: W_h2h int8 (per-row
// scale) in 64 VGPRs/thread; recurrence via sdot4; h carried as two-level i8
// in double-buffered LDS (1 barrier/step); reduce-scatter via width-16
// shuffles (static indices only). Zero cross-block traffic -> no protocols,
// no atomics, deadlock-impossible, deterministic.
// Thread map: rg = tid>>4 owns rows [8rg,8rg+8); kc = tid&15 owns k-range
// [32kc,32kc+32). Owner lanes (kc<8) run the epilogue for row 8rg+(kc&7).
// ---------------------------------------------------------------------------
template <bool PRE>
__global__ __launch_bounds__(1024, 4) void rnn_1cu(
    const float* __restrict__ x, const float* __restrict__ noise,
    const float* __restrict__ W_i2h, const float* __restrict__ b_i2h,
    const float* __restrict__ W_h2h, const float* __restrict__ b_h2h,
    const int* __restrict__ taup, const int* __restrict__ dtp,
    const float* __restrict__ xi_pre, float* __restrict__ out_rnn) {
  __shared__ char ha_s[2][16 * 48];  // level-1 bytes; chunk stride 48 (banks)
  __shared__ char hb_s[2][16 * 48];  // level-2 bytes
  __shared__ float x_s[2][I_];
  __shared__ unsigned wi_s[H_ * 12];  // (!PRE) f16x2[8] + bias f32; stride 48B

  const int tid = threadIdx.x;
  const int b = blockIdx.x;
  const int rg = tid >> 4;
  const int kc = tid & 15;

  const float alpha = (float)dtp[0] / (float)taup[0];
  const float nzscale = (float)(sqrt(2.0 * (double)alpha) * 0.01);

  // ---- setup: two-pass W quantization into 64 VGPRs ----
  const float* wbase = W_h2h + (size_t)(8 * rg) * H_ + 32 * kc;
  float m[8];
#pragma unroll
  for (int ro = 0; ro < 8; ++ro) {
    float mx = 0.f;
#pragma unroll
    for (int j = 0; j < 8; ++j) {
      const float4 f = *(const float4*)(wbase + (size_t)ro * H_ + 4 * j);
      mx = fmaxf(mx, fmaxf(fmaxf(fabsf(f.x), fabsf(f.y)),
                           fmaxf(fabsf(f.z), fabsf(f.w))));
    }
    m[ro] = mx;
  }
#pragma unroll
  for (int hop = 1; hop <= 8; hop <<= 1)
#pragma unroll
    for (int ro = 0; ro < 8; ++ro)
      m[ro] = fmaxf(m[ro], __shfl_xor(m[ro], hop, 16));
  unsigned wreg[64];
#pragma unroll
  for (int ro = 0; ro < 8; ++ro) {
    const float inv = (m[ro] > 0.f) ? 127.0f / m[ro] : 0.f;
#pragma unroll
    for (int j = 0; j < 8; ++j) {
      const float4 f = *(const float4*)(wbase + (size_t)ro * H_ + 4 * j);
      const int q0 = (int)rintf(f.x * inv), q1 = (int)rintf(f.y * inv);
      const int q2 = (int)rintf(f.z * inv), q3 = (int)rintf(f.w * inv);
      wreg[ro * 8 + j] = (unsigned)(q0 & 255) | ((unsigned)(q1 & 255) << 8) |
                         ((unsigned)(q2 & 255) << 16) |
                         ((unsigned)(q3 & 255) << 24);
    }
  }
  // s_own for row 8rg+(kc&7): static cndmask tree (no dynamic reg indexing)
  const float m01 = (kc & 1) ? m[1] : m[0];
  const float m23 = (kc & 1) ? m[3] : m[2];
  const float m45 = (kc & 1) ? m[5] : m[4];
  const float m67 = (kc & 1) ? m[7] : m[6];
  const float mlo = (kc & 2) ? m23 : m01;
  const float mhi = (kc & 2) ? m67 : m45;
  const float s_own = ((kc & 4) ? mhi : mlo) * (1.0f / 127.0f);

  if (!PRE && tid < H_) {  // W_i2h rows as f16 pairs + fused bias
    const float* wr = W_i2h + (size_t)tid * I_;
#pragma unroll
    for (int i2 = 0; i2 < 8; ++i2) {
      const unsigned short lo =
          __builtin_bit_cast(unsigned short, (_Float16)wr[2 * i2]);
      const unsigned short hi =
          __builtin_bit_cast(unsigned short, (_Float16)wr[2 * i2 + 1]);
      wi_s[tid * 12 + i2] = (unsigned)lo | ((unsigned)hi << 16);
    }
    wi_s[tid * 12 + 8] = __float_as_uint(b_i2h[tid] + b_h2h[tid]);
  }
  if (tid < 768) {
    ha_s[0][tid] = 0; ha_s[1][tid] = 0;
    hb_s[0][tid] = 0; hb_s[1][tid] = 0;
  }
  if (tid < I_) x_s[0][tid] = x[(size_t)b * T_ * I_ + tid];
  if (tid < H_) out_rnn[(size_t)b * (T_ + 1) * H_ + tid] = 0.f;
  __syncthreads();

  const int r_own = 8 * rg + (kc & 7);
  const bool owner = (kc < 8);
  const size_t nbase = (size_t)b * T_ * H_;
  const size_t obase = (size_t)b * (T_ + 1) * H_;

  for (int t = 0; t < T_; ++t) {
    const int p = t & 1;
    // prefetch per-step globals (consumed at epilogue; hide under dots)
    float nz = 0.f, xiv = 0.f;
    if (owner) {
      nz = noise[nbase + (size_t)t * H_ + r_own];
      if (PRE) xiv = xi_pre[nbase + (size_t)t * H_ + r_own];
    }
    if (tid < I_) {
      const int tn = (t < T_ - 1) ? t + 1 : t;
      x_s[p ^ 1][tid] = x[((size_t)b * T_ + tn) * I_ + tid];
    }
    // h(t) two-level bytes for my k-chunk
    const char* hap = &ha_s[p][kc * 48];
    const char* hbp = &hb_s[p][kc * 48];
    const uint4 A0 = *(const uint4*)hap;
    const uint4 A1 = *(const uint4*)(hap + 16);
    const uint4 B0 = *(const uint4*)hbp;
    const uint4 B1 = *(const uint4*)(hbp + 16);
    float v[8];
#pragma unroll
    for (int ro = 0; ro < 8; ++ro) {
      int a = 0, bb = 0;
      a = sdot4(wreg[ro * 8 + 0], A0.x, a);
      a = sdot4(wreg[ro * 8 + 1], A0.y, a);
      a = sdot4(wreg[ro * 8 + 2], A0.z, a);
      a = sdot4(wreg[ro * 8 + 3], A0.w, a);
      a = sdot4(wreg[ro * 8 + 4], A1.x, a);
      a = sdot4(wreg[ro * 8 + 5], A1.y, a);
      a = sdot4(wreg[ro * 8 + 6], A1.z, a);
      a = sdot4(wreg[ro * 8 + 7], A1.w, a);
      bb = sdot4(wreg[ro * 8 + 0], B0.x, bb);
      bb = sdot4(wreg[ro * 8 + 1], B0.y, bb);
      bb = sdot4(wreg[ro * 8 + 2], B0.z, bb);
      bb = sdot4(wreg[ro * 8 + 3], B0.w, bb);
      bb = sdot4(wreg[ro * 8 + 4], B1.x, bb);
      bb = sdot4(wreg[ro * 8 + 5], B1.y, bb);
      bb = sdot4(wreg[ro * 8 + 6], B1.z, bb);
      bb = sdot4(wreg[ro * 8 + 7], B1.w, bb);
      v[ro] = (float)a * S1q + (float)bb * S2q;
    }
    // reduce-scatter across the 16 kc lanes (static indices throughout):
#pragma unroll
    for (int ro = 0; ro < 8; ++ro) v[ro] += __shfl_xor(v[ro], 8, 16);
#pragma unroll
    for (int j = 0; j < 4; ++j) {
      const float tl = __shfl_xor(v[j], 4, 16);
      const float th = __shfl_xor(v[j + 4], 4, 16);
      v[j] = (kc & 4) ? (v[j + 4] + th) : (v[j] + tl);
    }
#pragma unroll
    for (int j = 0; j < 2; ++j) {
      const float tl = __shfl_xor(v[j], 2, 16);
      const float th = __shfl_xor(v[j + 2], 2, 16);
      v[j] = (kc & 2) ? (v[j + 2] + th) : (v[j] + tl);
    }
    float rec;
    {
      const float tl = __shfl_xor(v[0], 1, 16);
      const float th = __shfl_xor(v[1], 1, 16);
      rec = (kc & 1) ? (v[1] + th) : (v[0] + tl);
    }
    // epilogue: owner lane finishes row r_own
    if (owner) {
      float xfull;
      if (PRE) {
        xfull = xiv;
      } else {
        const uint4 w0 = *(const uint4*)&wi_s[r_own * 12];
        const uint4 w1 = *(const uint4*)&wi_s[r_own * 12 + 4];
        float s = __uint_as_float(wi_s[r_own * 12 + 8]);
        s += f16lo(w0.x) * x_s[p][0] + f16hi(w0.x) * x_s[p][1];
        s += f16lo(w0.y) * x_s[p][2] + f16hi(w0.y) * x_s[p][3];
        s += f16lo(w0.z) * x_s[p][4] + f16hi(w0.z) * x_s[p][5];
        s += f16lo(w0.w) * x_s[p][6] + f16hi(w0.w) * x_s[p][7];
        s += f16lo(w1.x) * x_s[p][8] + f16hi(w1.x) * x_s[p][9];
        s += f16lo(w1.y) * x_s[p][10] + f16hi(w1.y) * x_s[p][11];
        s += f16lo(w1.z) * x_s[p][12] + f16hi(w1.z) * x_s[p][13];
        s += f16lo(w1.w) * x_s[p][14] + f16hi(w1.w) * x_s[p][15];
        xfull = s;
      }
      const float pre = alpha * (xfull + rec * s_own) + nzscale * nz;
      const float h = fmaxf(pre, 0.f);
      out_rnn[obase + (size_t)(t + 1) * H_ + r_own] = h;
      int aq = (int)rintf(h * IS1q);
      aq = min(aq, 127);
      const float res = h - (float)aq * S1q;
      const int bq = (int)rintf(res * IS2q);
      const int c = r_own >> 5, wi2 = r_own & 31;
      ha_s[p ^ 1][c * 48 + wi2] = (char)aq;
      hb_s[p ^ 1][c * 48 + wi2] = (char)bq;
    }
    __syncthreads();  // h(t+1) + x(t+1) staged; double-buffers flip
  }
}

// ---------------------------------------------------------------------------
// Post-pass: out_net[b][t] = W_h2o . h_ex(b,t) + b_h2o (t>=1), zeros at t=0.
// ---------------------------------------------------------------------------
__global__ __launch_bounds__(256) void h2o_kernel(
    const float* __restrict__ out_rnn, const float* __restrict__ W_h2o,
    const float* __restrict__ b_h2o, float* __restrict__ out_net) {
  __shared__ float w3[3 * 416];
  const int tid = threadIdx.x;
  for (int idx = tid; idx < O_ * NEX_; idx += 256) {
    const int o = idx / NEX_, e = idx - o * NEX_;
    w3[o * 416 + e] = W_h2o[idx];
  }
  __syncthreads();
  const int wv = tid >> 6, ln = tid & 63;
  const int task = blockIdx.x * 4 + wv;
  if (task >= B_ * (T_ + 1)) return;
  const int bb = task / (T_ + 1), t = task - bb * (T_ + 1);
  float* dst = out_net + (size_t)task * O_;
  if (t == 0) {
    if (ln < O_) dst[ln] = 0.f;
    return;
  }
  const float* hrow = out_rnn + (size_t)task * H_ + NIN_;
  float a0 = 0.f, a1 = 0.f, a2 = 0.f;
  for (int k = ln; k < NEX_; k += 64) {
    const float hv = hrow[k];
    a0 += hv * w3[k];
    a1 += hv * w3[416 + k];
    a2 += hv * w3[832 + k];
  }
#pragma unroll
  for (int off = 32; off >= 1; off >>= 1) {
    a0 += __shfl_xor(a0, off, 64);
    a1 += __shfl_xor(a1, off, 64);
    a2 += __shfl_xor(a2, off, 64);
  }
  if (ln == 0) {
    dst[0] = a0 + b_h2o[0];
    dst[1] = a1 + b_h2o[1];
    dst[2] = a2 + b_h2o[2];
  }
}

extern "C" void kernel_launch(void* const* d_in, const int* in_sizes, int n_in,
                              void* d_out, int out_size, void* d_ws,
                              size_t ws_size, hipStream_t stream) {
  const float* x = (const float*)d_in[0];
  const float* noise = (const float*)d_in[1];
  const float* W_i2h = (const float*)d_in[2];
  const float* b_i2h = (const float*)d_in[3];
  const float* W_h2h = (const float*)d_in[4];
  const float* b_h2h = (const float*)d_in[5];
  const float* W_h2o = (const float*)d_in[6];
  const float* b_h2o = (const float*)d_in[7];
  const int* tau = (const int*)d_in[8];
  const int* dt = (const int*)d_in[9];

  float* out_net = (float*)d_out;
  float* out_rnn = (float*)d_out + (size_t)B_ * (T_ + 1) * O_;

  if (d_ws != nullptr && ws_size >= XI_BYTES) {
    float* xi = (float*)d_ws;
    hipLaunchKernelGGL(xi_pre_kernel, dim3(2048), dim3(256), 0, stream, x,
                       W_i2h, b_i2h, b_h2h, xi);
    hipLaunchKernelGGL((rnn_1cu<true>), dim3(B_), dim3(1024), 0, stream, x,
                       noise, W_i2h, b_i2h, W_h2h, b_h2h, tau, dt, xi, out_rnn);
  } else {
    hipLaunchKernelGGL((rnn_1cu<false>), dim3(B_), dim3(1024), 0, stream, x,
                       noise, W_i2h, b_i2h, W_h2h, b_h2h, tau, dt,
                       (const float*)nullptr, out_rnn);
  }
  hipLaunchKernelGGL(h2o_kernel, dim3((B_ * (T_ + 1) + 3) / 4), dim3(256), 0,
                     stream, out_rnn, W_h2o, b_h2o, out_net);
}